// Round 9
// baseline (115.494 us; speedup 1.0000x reference)
//
#include <hip/hip_runtime.h>
#include <hip/hip_bf16.h>

// Shapes
#define B_SZ   256
#define C_SZ   1024
#define HW     49
#define KDIM   50176        // C*H*W
#define DHID   768
#define NCLS   5

typedef __bf16 bf16x8 __attribute__((ext_vector_type(8)));
typedef float  f32x4  __attribute__((ext_vector_type(4)));

#define GLOAD_LDS16(gsrc, ldst) \
  __builtin_amdgcn_global_load_lds((__attribute__((address_space(1))) void*)(gsrc), \
                                   (__attribute__((address_space(3))) void*)(ldst), 16, 0, 0)

// ---------------------------------------------------------------------------
// Kernel A: per-(b,c) spatial max, pcam = feat*max -> bf16 (ws), copy feat -> out
// ---------------------------------------------------------------------------
__global__ __launch_bounds__(256) void pcam_kernel(const float* __restrict__ feat,
                                                   float* __restrict__ feat_out,
                                                   __bf16* __restrict__ pcam) {
  __shared__ float sv[1568];
  __shared__ float smax[32];
  const int tid = threadIdx.x;
  const size_t base = (size_t)blockIdx.x * 1568;

  const float4* src4 = (const float4*)(feat + base);
  float4* dst4 = (float4*)(feat_out + base);
  #pragma unroll
  for (int i = 0; i < 2; ++i) {
    int idx = tid + i * 256;
    if (idx < 392) {
      float4 v = src4[idx];
      dst4[idx] = v;
      ((float4*)sv)[idx] = v;
    }
  }
  __syncthreads();

  {
    const int r = tid >> 3, p = tid & 7;
    float mx = -INFINITY;
    for (int i = p; i < HW; i += 8) mx = fmaxf(mx, sv[r * HW + i]);
    #pragma unroll
    for (int off = 1; off < 8; off <<= 1) mx = fmaxf(mx, __shfl_xor(mx, off));
    if (p == 0) smax[r] = mx;
  }
  __syncthreads();

  for (int i = tid; i < 1568; i += 256) {
    int r = (i * 1338) >> 16;        // i/49 exact for i<1568
    float v = sv[i] * smax[r];
    pcam[base + i] = (__bf16)v;
  }
}

// ---------------------------------------------------------------------------
// Kernel B (v7 = m97 clone): R1-R8 invariant: per-CU staged ingress pinned
// at ~21 GB/s with 1-2 big blocks/CU, regardless of DMA/reg staging, barrier
// type, prefetch depth, stride, run length. m97 (same chip+instruction) hit
// 52 GB/s/CU with THREE 4-wave blocks per CU (independent barrier domains
// cover each other's stage-drain stalls). This round tests exactly that:
//   - 256 threads (4 waves, 2x2 quadrants), 128x128 tile, BK=64
//   - single-buffered LDS: A bf16 16KB + B raw fp32 32KB = 48KB -> 3 blk/CU
//   - m97 schedule verbatim: STAGE(DMA); __syncthreads; COMPUTE; __syncthreads
//   - KSPLIT=64 -> 768 blocks, all resident; private partials, no atomics
// Source-side XOR swizzle (16B unit ^= row&7), linear LDS dest (m173).
// ---------------------------------------------------------------------------
#define BM 128
#define BN 128
#define BK 64
#define MT 2
#define NT 6
#define KSPLIT 64
#define KSTEPS 784          // KDIM/BK

__global__ __launch_bounds__(256, 3) void gemm1_kernel(const __bf16* __restrict__ pcam,
                                                       const float* __restrict__ W1,
                                                       float* __restrict__ h_part) {
  __shared__ __bf16 Asm[BM * BK];   // 16 KB (bf16)
  __shared__ float  Bsm[BN * BK];   // 32 KB (raw fp32)

  const int tid  = threadIdx.x;
  const int lane = tid & 63;
  const int w    = tid >> 6;        // 0..3
  const int wm   = w >> 1;          // 0..1 : 64-row slab
  const int wn   = w & 1;           // 0..1 : 64-col slab
  const int bx   = blockIdx.x;      // 0..11
  const int m0   = (bx & 1) * BM;
  const int n0   = (bx >> 1) * BN;
  const int ks   = blockIdx.y;
  const int s0   = (ks * KSTEPS) / KSPLIT;
  const int s1   = ((ks + 1) * KSTEPS) / KSPLIT;

  // A DMA: 4 instrs/thread-slot; 16B-unit ug=it*256+tid; row m=ug>>3
  // (8 units/row); source unit pre-swizzled ^(m&7).
  unsigned a_off[4];
  #pragma unroll
  for (int it = 0; it < 4; ++it) {
    const unsigned ug = it * 256 + tid;
    const unsigned m  = ug >> 3;
    a_off[it] = (unsigned)(m0 + m) * KDIM + (((ug & 7) ^ (m & 7)) * 8u);
  }
  // B DMA (fp32): 8 instrs; 16B-unit ug=it*256+tid; row r=ug>>4 (16/row);
  // 32B-granule g=(ug&15)>>1 swizzled ^(r&7), half=(ug&1).
  unsigned b_off[8];
  #pragma unroll
  for (int it = 0; it < 8; ++it) {
    const unsigned ug = it * 256 + tid;
    const unsigned r  = ug >> 4;
    const unsigned up = ug & 15;
    b_off[it] = (unsigned)(n0 + r) * KDIM + (((up >> 1) ^ (r & 7)) * 8u) + ((up & 1) * 4u);
  }

  f32x4 acc[4][4];
  #pragma unroll
  for (int i = 0; i < 4; ++i)
    #pragma unroll
    for (int j = 0; j < 4; ++j) acc[i][j] = f32x4{0.f, 0.f, 0.f, 0.f};

  const int j_ = lane >> 4;         // 0..3 : k-chunk / C-row group
  const int c_ = lane & 15;         // 0..15: fragment row/col

  for (int s = s0; s < s1; ++s) {
    // ---- STAGE: 12 DMA instrs/thread (A 4, B 8), linear LDS dest
    const unsigned ka = (unsigned)s * BK;
    #pragma unroll
    for (int it = 0; it < 4; ++it)
      GLOAD_LDS16(pcam + a_off[it] + ka, (char*)Asm + it * 4096 + w * 1024);
    #pragma unroll
    for (int it = 0; it < 8; ++it)
      GLOAD_LDS16(W1 + b_off[it] + ka, (char*)Bsm + it * 4096 + w * 1024);
    __syncthreads();   // drains DMA (vmcnt0) — other 2 blocks/CU cover the stall

    // ---- COMPUTE: 32 MFMAs (2 ksub x 4m x 4n)
    #pragma unroll
    for (int ksub = 0; ksub < 2; ++ksub) {
      const int u = ksub * 4 + j_;
      bf16x8 af[4];
      #pragma unroll
      for (int i = 0; i < 4; ++i) {
        const int m = wm * 64 + i * 16 + c_;
        af[i] = *(const bf16x8*)((const char*)Asm + m * 128 + ((u ^ (m & 7)) << 4));
      }
      bf16x8 bfr[4];
      #pragma unroll
      for (int jf = 0; jf < 4; ++jf) {
        const int r  = wn * 64 + jf * 16 + c_;
        const int gp = u ^ (r & 7);
        const f32x4 v0 = *(const f32x4*)((const char*)Bsm + r * 256 + gp * 32);
        const f32x4 v1 = *(const f32x4*)((const char*)Bsm + r * 256 + gp * 32 + 16);
        bfr[jf][0] = (__bf16)v0[0]; bfr[jf][1] = (__bf16)v0[1];
        bfr[jf][2] = (__bf16)v0[2]; bfr[jf][3] = (__bf16)v0[3];
        bfr[jf][4] = (__bf16)v1[0]; bfr[jf][5] = (__bf16)v1[1];
        bfr[jf][6] = (__bf16)v1[2]; bfr[jf][7] = (__bf16)v1[3];
      }
      #pragma unroll
      for (int i = 0; i < 4; ++i)
        #pragma unroll
        for (int jf = 0; jf < 4; ++jf)
          acc[i][jf] = __builtin_amdgcn_mfma_f32_16x16x32_bf16(af[i], bfr[jf], acc[i][jf], 0, 0, 0);
    }
    __syncthreads();   // reads done before next STAGE overwrites
  }

  // ---- epilogue: private partial slice [ks][n][m], coalesced float4 stores
  float* out = h_part + (size_t)ks * DHID * B_SZ;
  #pragma unroll
  for (int i = 0; i < 4; ++i) {
    const int mb = m0 + wm * 64 + i * 16 + j_ * 4;
    #pragma unroll
    for (int jf = 0; jf < 4; ++jf) {
      const int n = n0 + wn * 64 + jf * 16 + c_;
      *(f32x4*)(out + (size_t)n * B_SZ + mb) = acc[i][jf];
    }
  }
}

// ---------------------------------------------------------------------------
// Kernel C: reduce split-K partials, add b1, relu -> h[m][n]
// ---------------------------------------------------------------------------
__global__ __launch_bounds__(256) void reduce_kernel(const float* __restrict__ h_part,
                                                     const float* __restrict__ b1,
                                                     float* __restrict__ h) {
  const int n = blockIdx.x;
  const int m = threadIdx.x;
  float s = 0.f;
  #pragma unroll 8
  for (int ks = 0; ks < KSPLIT; ++ks)
    s += h_part[((size_t)ks * DHID + n) * B_SZ + m];
  float v = s + b1[n];
  h[(size_t)m * DHID + n] = v > 0.f ? v : 0.f;
}

// ---------------------------------------------------------------------------
// Kernel D: logits = h @ W2^T + b2. One wave per batch row.
// ---------------------------------------------------------------------------
__global__ __launch_bounds__(64) void head_kernel(const float* __restrict__ h,
                                                  const float* __restrict__ W2,
                                                  const float* __restrict__ b2,
                                                  float* __restrict__ logits) {
  const int m = blockIdx.x;
  const int lane = threadIdx.x;
  float hv[12];
  #pragma unroll
  for (int j = 0; j < 12; ++j) hv[j] = h[(size_t)m * DHID + j * 64 + lane];
  #pragma unroll
  for (int c = 0; c < NCLS; ++c) {
    float s = 0.f;
    #pragma unroll
    for (int j = 0; j < 12; ++j) s += hv[j] * W2[c * DHID + j * 64 + lane];
    #pragma unroll
    for (int off = 32; off > 0; off >>= 1) s += __shfl_xor(s, off);
    if (lane == 0) logits[m * NCLS + c] = s + b2[c];
  }
}

// ---------------------------------------------------------------------------
extern "C" void kernel_launch(void* const* d_in, const int* in_sizes, int n_in,
                              void* d_out, int out_size, void* d_ws, size_t ws_size,
                              hipStream_t stream) {
  const float* feat = (const float*)d_in[0];
  const float* W1   = (const float*)d_in[1];
  const float* b1   = (const float*)d_in[2];
  const float* W2   = (const float*)d_in[3];
  const float* b2   = (const float*)d_in[4];

  float* logits   = (float*)d_out;
  float* feat_out = (float*)d_out + (size_t)B_SZ * NCLS;

  char* ws = (char*)d_ws;
  __bf16* pcam   = (__bf16*)ws;                                   // 25.7 MB
  float*  h_part = (float*)(ws + (size_t)B_SZ * KDIM * 2);        // 64*768*256*4 = 50.3 MB
  float*  h      = (float*)(ws + (size_t)B_SZ * KDIM * 2
                               + (size_t)KSPLIT * DHID * B_SZ * 4); // 786 KB

  pcam_kernel<<<(B_SZ * C_SZ) / 32, 256, 0, stream>>>(feat, feat_out, pcam);
  gemm1_kernel<<<dim3(MT * NT, KSPLIT), 256, 0, stream>>>(pcam, W1, h_part);
  reduce_kernel<<<DHID, 256, 0, stream>>>(h_part, b1, h);
  head_kernel<<<B_SZ, 64, 0, stream>>>(h, W2, b2, logits);
}

// Round 10
// 106.647 us; speedup vs baseline: 1.0829x; 1.0829x over previous
//
#include <hip/hip_runtime.h>
#include <hip/hip_bf16.h>

// Shapes
#define B_SZ   256
#define C_SZ   1024
#define HW     49
#define KDIM   50176        // C*H*W
#define DHID   768
#define NCLS   5

typedef __bf16 bf16x8 __attribute__((ext_vector_type(8)));
typedef float  f32x4  __attribute__((ext_vector_type(4)));

#define GLOAD_LDS16(gsrc, ldst) \
  __builtin_amdgcn_global_load_lds((__attribute__((address_space(1))) void*)(gsrc), \
                                   (__attribute__((address_space(3))) void*)(ldst), 16, 0, 0)

// ---------------------------------------------------------------------------
// Kernel A: per-(b,c) spatial max, pcam = feat*max -> bf16 (ws), copy feat -> out
// ---------------------------------------------------------------------------
__global__ __launch_bounds__(256) void pcam_kernel(const float* __restrict__ feat,
                                                   float* __restrict__ feat_out,
                                                   __bf16* __restrict__ pcam) {
  __shared__ float sv[1568];
  __shared__ float smax[32];
  const int tid = threadIdx.x;
  const size_t base = (size_t)blockIdx.x * 1568;

  const float4* src4 = (const float4*)(feat + base);
  float4* dst4 = (float4*)(feat_out + base);
  #pragma unroll
  for (int i = 0; i < 2; ++i) {
    int idx = tid + i * 256;
    if (idx < 392) {
      float4 v = src4[idx];
      dst4[idx] = v;
      ((float4*)sv)[idx] = v;
    }
  }
  __syncthreads();

  {
    const int r = tid >> 3, p = tid & 7;
    float mx = -INFINITY;
    for (int i = p; i < HW; i += 8) mx = fmaxf(mx, sv[r * HW + i]);
    #pragma unroll
    for (int off = 1; off < 8; off <<= 1) mx = fmaxf(mx, __shfl_xor(mx, off));
    if (p == 0) smax[r] = mx;
  }
  __syncthreads();

  for (int i = tid; i < 1568; i += 256) {
    int r = (i * 1338) >> 16;        // i/49 exact for i<1568
    float v = sv[i] * smax[r];
    pcam[base + i] = (__bf16)v;
  }
}

// ---------------------------------------------------------------------------
// Kernel B (v8 = MIN-BYTES + FAT-STEPS): R1-R9 invariant: staged ingress runs
// ~21 GB/s/CU (~2.2us per 48KB CU-step) regardless of ALL pipeline structure.
// Two untested levers, pulled together:
//   (1) total ingress 462 -> 231 MB: BM=256 (full M, W1 read ONCE),
//       BN=256 -> NT=3 (pcam read only 3x = 77 MB).
//   (2) bytes/step 48 -> 96 KB, steps/block ~9.2: BK=64, single-buffered
//       96KB LDS (A bf16 32KB + B raw fp32 64KB), 1 block/CU.
// KSPLIT=85 -> 255 blocks (1/CU). m97 schedule: DMA-stage; sync; compute;
// sync. Source-side XOR swizzle, linear LDS dest: A unit^=(m&7),
// B 32B-granule^=(r&7) -> fragment reads 2-way max.
// Private partials [ks][n][m], no atomics.
// ---------------------------------------------------------------------------
#define BM 256
#define BN 256
#define BK 64
#define NT 3
#define KSPLIT 85
#define KSTEPS 784          // KDIM/BK

__global__ __launch_bounds__(512, 2) void gemm1_kernel(const __bf16* __restrict__ pcam,
                                                       const float* __restrict__ W1,
                                                       float* __restrict__ h_part) {
  __shared__ __bf16 Asm[BM * BK];   // 32 KB (bf16)
  __shared__ float  Bsm[BN * BK];   // 64 KB (raw fp32)

  const int tid  = threadIdx.x;
  const int lane = tid & 63;
  const int w    = tid >> 6;        // 0..7
  const int wm   = w >> 2;          // 0..1 : 128-row slab
  const int wn   = w & 3;           // 0..3 : 64-col slab
  const int n0   = blockIdx.x * BN; // 0..2 -> 0,256,512
  const int ks   = blockIdx.y;      // 0..84
  const int s0   = (ks * KSTEPS) / KSPLIT;
  const int s1   = ((ks + 1) * KSTEPS) / KSPLIT;

  // A DMA: 4 instrs/thread; 16B-unit ug=it*512+tid; row m=ug>>3 (8 units/row);
  // source unit pre-swizzled ^(m&7).
  unsigned a_off[4];
  #pragma unroll
  for (int it = 0; it < 4; ++it) {
    const unsigned ug = it * 512 + tid;
    const unsigned m  = ug >> 3;
    a_off[it] = m * (unsigned)KDIM + (((ug & 7) ^ (m & 7)) * 8u);
  }
  // B DMA (raw fp32): 8 instrs/thread; 16B-unit ug=it*512+tid; row r=ug>>4
  // (16 units/row); 32B-granule (ug&15)>>1 swizzled ^(r&7), half=(ug&1).
  unsigned b_off[8];
  #pragma unroll
  for (int it = 0; it < 8; ++it) {
    const unsigned ug = it * 512 + tid;
    const unsigned r  = ug >> 4;
    const unsigned up = ug & 15;
    b_off[it] = (unsigned)(n0 + r) * KDIM + ((((up >> 1) ^ (r & 7)) * 8u) + ((up & 1) * 4u));
  }

  f32x4 acc[8][4];
  #pragma unroll
  for (int i = 0; i < 8; ++i)
    #pragma unroll
    for (int j = 0; j < 4; ++j) acc[i][j] = f32x4{0.f, 0.f, 0.f, 0.f};

  const int j_ = lane >> 4;         // 0..3
  const int c_ = lane & 15;         // 0..15

  for (int s = s0; s < s1; ++s) {
    // ---- STAGE: 12 DMA instrs/thread (A 4, B 8), linear LDS dest
    const unsigned ka = (unsigned)s * BK;
    #pragma unroll
    for (int it = 0; it < 4; ++it)
      GLOAD_LDS16(pcam + a_off[it] + ka, (char*)Asm + it * 8192 + w * 1024);
    #pragma unroll
    for (int it = 0; it < 8; ++it)
      GLOAD_LDS16(W1 + b_off[it] + ka, (char*)Bsm + it * 8192 + w * 1024);
    __syncthreads();   // drain DMAs (vmcnt0), rendezvous

    // ---- COMPUTE: 64 MFMAs (2 ksub x 8m x 4n)
    #pragma unroll
    for (int ksub = 0; ksub < 2; ++ksub) {
      const int u = ksub * 4 + j_;
      bf16x8 af[8];
      #pragma unroll
      for (int i = 0; i < 8; ++i) {
        const int m = wm * 128 + i * 16 + c_;
        af[i] = *(const bf16x8*)((const char*)Asm + m * 128 + ((u ^ (m & 7)) << 4));
      }
      #pragma unroll
      for (int jf = 0; jf < 4; ++jf) {
        const int r  = wn * 64 + jf * 16 + c_;
        const int gp = u ^ (r & 7);
        const f32x4 v0 = *(const f32x4*)((const char*)Bsm + r * 256 + gp * 32);
        const f32x4 v1 = *(const f32x4*)((const char*)Bsm + r * 256 + gp * 32 + 16);
        bf16x8 bfr;
        bfr[0] = (__bf16)v0[0]; bfr[1] = (__bf16)v0[1];
        bfr[2] = (__bf16)v0[2]; bfr[3] = (__bf16)v0[3];
        bfr[4] = (__bf16)v1[0]; bfr[5] = (__bf16)v1[1];
        bfr[6] = (__bf16)v1[2]; bfr[7] = (__bf16)v1[3];
        #pragma unroll
        for (int i = 0; i < 8; ++i)
          acc[i][jf] = __builtin_amdgcn_mfma_f32_16x16x32_bf16(af[i], bfr, acc[i][jf], 0, 0, 0);
      }
    }
    __syncthreads();   // reads done before next STAGE overwrites
  }

  // ---- epilogue: private partial slice [ks][n][m], coalesced float4 stores
  float* out = h_part + (size_t)ks * DHID * B_SZ;
  #pragma unroll
  for (int i = 0; i < 8; ++i) {
    const int mb = wm * 128 + i * 16 + j_ * 4;
    #pragma unroll
    for (int jf = 0; jf < 4; ++jf) {
      const int n = n0 + wn * 64 + jf * 16 + c_;
      *(f32x4*)(out + (size_t)n * B_SZ + mb) = acc[i][jf];
    }
  }
}

// ---------------------------------------------------------------------------
// Kernel C: reduce split-K partials, add b1, relu -> h[m][n]
// ---------------------------------------------------------------------------
__global__ __launch_bounds__(256) void reduce_kernel(const float* __restrict__ h_part,
                                                     const float* __restrict__ b1,
                                                     float* __restrict__ h) {
  const int n = blockIdx.x;
  const int m = threadIdx.x;
  float s = 0.f;
  #pragma unroll 5
  for (int ks = 0; ks < KSPLIT; ++ks)
    s += h_part[((size_t)ks * DHID + n) * B_SZ + m];
  float v = s + b1[n];
  h[(size_t)m * DHID + n] = v > 0.f ? v : 0.f;
}

// ---------------------------------------------------------------------------
// Kernel D: logits = h @ W2^T + b2. One wave per batch row.
// ---------------------------------------------------------------------------
__global__ __launch_bounds__(64) void head_kernel(const float* __restrict__ h,
                                                  const float* __restrict__ W2,
                                                  const float* __restrict__ b2,
                                                  float* __restrict__ logits) {
  const int m = blockIdx.x;
  const int lane = threadIdx.x;
  float hv[12];
  #pragma unroll
  for (int j = 0; j < 12; ++j) hv[j] = h[(size_t)m * DHID + j * 64 + lane];
  #pragma unroll
  for (int c = 0; c < NCLS; ++c) {
    float s = 0.f;
    #pragma unroll
    for (int j = 0; j < 12; ++j) s += hv[j] * W2[c * DHID + j * 64 + lane];
    #pragma unroll
    for (int off = 32; off > 0; off >>= 1) s += __shfl_xor(s, off);
    if (lane == 0) logits[m * NCLS + c] = s + b2[c];
  }
}

// ---------------------------------------------------------------------------
extern "C" void kernel_launch(void* const* d_in, const int* in_sizes, int n_in,
                              void* d_out, int out_size, void* d_ws, size_t ws_size,
                              hipStream_t stream) {
  const float* feat = (const float*)d_in[0];
  const float* W1   = (const float*)d_in[1];
  const float* b1   = (const float*)d_in[2];
  const float* W2   = (const float*)d_in[3];
  const float* b2   = (const float*)d_in[4];

  float* logits   = (float*)d_out;
  float* feat_out = (float*)d_out + (size_t)B_SZ * NCLS;

  char* ws = (char*)d_ws;
  __bf16* pcam   = (__bf16*)ws;                                   // 25.7 MB
  float*  h_part = (float*)(ws + (size_t)B_SZ * KDIM * 2);        // 85*768*256*4 = 66.8 MB
  float*  h      = (float*)(ws + (size_t)B_SZ * KDIM * 2
                               + (size_t)KSPLIT * DHID * B_SZ * 4); // 786 KB

  pcam_kernel<<<(B_SZ * C_SZ) / 32, 256, 0, stream>>>(feat, feat_out, pcam);
  gemm1_kernel<<<dim3(NT, KSPLIT), 512, 0, stream>>>(pcam, W1, h_part);
  reduce_kernel<<<DHID, 256, 0, stream>>>(h_part, b1, h);
  head_kernel<<<B_SZ, 64, 0, stream>>>(h, W2, b2, logits);
}

// Round 11
// 103.858 us; speedup vs baseline: 1.1120x; 1.0269x over previous
//
#include <hip/hip_runtime.h>
#include <hip/hip_bf16.h>

// Shapes
#define B_SZ   256
#define C_SZ   1024
#define HW     49
#define KDIM   50176        // C*H*W
#define DHID   768
#define NCLS   5

typedef __bf16 bf16x8 __attribute__((ext_vector_type(8)));
typedef float  f32x4  __attribute__((ext_vector_type(4)));

// lgkmcnt-only barrier: orders LDS writes/reads without draining vmcnt,
// so global-load streams stay in flight across it (R5).
#define BARRIER() do { \
    asm volatile("s_waitcnt lgkmcnt(0)" ::: "memory"); \
    __builtin_amdgcn_s_barrier(); \
    asm volatile("" ::: "memory"); \
  } while (0)

// ---------------------------------------------------------------------------
// Kernel A: per-(b,c) spatial max, pcam = feat*max -> bf16 (ws), copy feat -> out
// ---------------------------------------------------------------------------
__global__ __launch_bounds__(256) void pcam_kernel(const float* __restrict__ feat,
                                                   float* __restrict__ feat_out,
                                                   __bf16* __restrict__ pcam) {
  __shared__ float sv[1568];
  __shared__ float smax[32];
  const int tid = threadIdx.x;
  const size_t base = (size_t)blockIdx.x * 1568;

  const float4* src4 = (const float4*)(feat + base);
  float4* dst4 = (float4*)(feat_out + base);
  #pragma unroll
  for (int i = 0; i < 2; ++i) {
    int idx = tid + i * 256;
    if (idx < 392) {
      float4 v = src4[idx];
      dst4[idx] = v;
      ((float4*)sv)[idx] = v;
    }
  }
  __syncthreads();

  {
    const int r = tid >> 3, p = tid & 7;
    float mx = -INFINITY;
    for (int i = p; i < HW; i += 8) mx = fmaxf(mx, sv[r * HW + i]);
    #pragma unroll
    for (int off = 1; off < 8; off <<= 1) mx = fmaxf(mx, __shfl_xor(mx, off));
    if (p == 0) smax[r] = mx;
  }
  __syncthreads();

  for (int i = tid; i < 1568; i += 256) {
    int r = (i * 1338) >> 16;        // i/49 exact for i<1568
    float v = sv[i] * smax[r];
    pcam[base + i] = (__bf16)v;
  }
}

// ---------------------------------------------------------------------------
// Kernel B (v9 = BARRIER-FREE B-STREAM): R1-R10 invariant: duration ~80us
// regardless of bytes (460MB@5.3TB/s == 230MB@3TB/s) -> the LDS-staging
// barrier quantization IS the cap, not bandwidth. Key insight: W1 has ZERO
// cross-wave reuse in this layout -> B never needs LDS. Each lane loads its
// MFMA B-fragment straight to registers (row n0+w*16+(lane&15), 8 fp32 =
// 2x dwordx4 + cvt). No vmcnt(0) ever touches the B stream; hardware TLP
// schedules it like a pure streaming kernel (pcam/fill run 7 TB/s this way).
// Only A (pcam, 26MB, L3-resident) is LDS-staged: double-buffered,
// reg-staged, lgkmcnt-only barriers. BM=256 (W1 read once), BN=128 (8 waves
// x 16 cols), KC=64, KSPLIT=42 -> 252 blocks; partials 33MB; no atomics.
// A-LDS XOR swizzle: 16B-unit ^= (m&7) via pre-swizzled SOURCE, linear dest.
// ---------------------------------------------------------------------------
#define BM 256
#define BN 128
#define KC 64
#define NT 6
#define KSPLIT 42
#define KSTEPS 784          // KDIM/KC

__global__ __launch_bounds__(512, 2) void gemm1_kernel(const __bf16* __restrict__ pcam,
                                                       const float* __restrict__ W1,
                                                       float* __restrict__ h_part) {
  __shared__ __bf16 Asm[2][BM * KC];   // 2 x 32 KB

  const int tid  = threadIdx.x;
  const int lane = tid & 63;
  const int w    = tid >> 6;        // 0..7 : 16-col n-slab per wave
  const int n0   = blockIdx.x * BN;
  const int ks   = blockIdx.y;
  const int s0   = (ks * KSTEPS) / KSPLIT;
  const int s1   = ((ks + 1) * KSTEPS) / KSPLIT;

  // B direct-fragment base: lane l -> W1 row n0+w*16+(l&15), k-chunk (l>>4)*8
  const float* bbase = W1 + (size_t)(n0 + w * 16 + (lane & 15)) * KDIM + (lane >> 4) * 8;

  // A staging: 2048 16B-units per chunk (256 rows x 8 units), 4 per thread.
  // Source unit pre-swizzled ^(m&7); LDS written linear.
  unsigned a_off[4];
  int      a_lds[4];
  #pragma unroll
  for (int it = 0; it < 4; ++it) {
    const unsigned ug = it * 512 + tid;   // 0..2047
    const unsigned m  = ug >> 3;
    const unsigned u  = ug & 7;
    a_off[it] = m * (unsigned)KDIM + ((u ^ (m & 7)) * 8u);
    a_lds[it] = (int)(ug * 8);            // bf16 index
  }

  f32x4 acc[16];
  #pragma unroll
  for (int i = 0; i < 16; ++i) acc[i] = f32x4{0.f, 0.f, 0.f, 0.f};

  bf16x8 ar[4];   // A-stage registers

#define LOAD_A(s) do { \
    _Pragma("unroll") \
    for (int it = 0; it < 4; ++it) \
      ar[it] = *(const bf16x8*)(pcam + a_off[it] + (unsigned)(s) * KC); \
  } while (0)

#define WRITE_A(bi) do { \
    _Pragma("unroll") \
    for (int it = 0; it < 4; ++it) \
      *(bf16x8*)(&Asm[bi][a_lds[it]]) = ar[it]; \
  } while (0)

#define COMPUTE(bi, s) do { \
    _Pragma("unroll") \
    for (int ksub = 0; ksub < 2; ++ksub) { \
      const f32x4 v0 = *(const f32x4*)(bbase + (size_t)(s) * KC + ksub * 32); \
      const f32x4 v1 = *(const f32x4*)(bbase + (size_t)(s) * KC + ksub * 32 + 4); \
      bf16x8 bfr; \
      bfr[0] = (__bf16)v0[0]; bfr[1] = (__bf16)v0[1]; \
      bfr[2] = (__bf16)v0[2]; bfr[3] = (__bf16)v0[3]; \
      bfr[4] = (__bf16)v1[0]; bfr[5] = (__bf16)v1[1]; \
      bfr[6] = (__bf16)v1[2]; bfr[7] = (__bf16)v1[3]; \
      const int u = ksub * 4 + (lane >> 4); \
      _Pragma("unroll") \
      for (int i = 0; i < 16; ++i) { \
        const int m = i * 16 + (lane & 15); \
        const bf16x8 af = *(const bf16x8*)((const char*)Asm[bi] + m * 128 + ((u ^ (m & 7)) << 4)); \
        acc[i] = __builtin_amdgcn_mfma_f32_16x16x32_bf16(af, bfr, acc[i], 0, 0, 0); \
      } \
    } \
  } while (0)

  // ---- prologue: stage A(s0) into buf0
  LOAD_A(s0);
  WRITE_A(0);
  BARRIER();

  for (int s = s0; s < s1; ++s) {
    const int cur = (s - s0) & 1;
    if (s + 1 < s1) LOAD_A(s + 1);      // global->regs, no barrier dependency
    COMPUTE(cur, s);                     // B streams straight from global
    if (s + 1 < s1) WRITE_A(cur ^ 1);
    BARRIER();                           // lgkmcnt only — B stream unaffected
  }

  // ---- epilogue: private partial slice [ks][n][m], coalesced float4 stores
  float* out = h_part + (size_t)ks * DHID * B_SZ;
  const int n = n0 + w * 16 + (lane & 15);
  #pragma unroll
  for (int i = 0; i < 16; ++i) {
    const int mb = i * 16 + (lane >> 4) * 4;
    *(f32x4*)(out + (size_t)n * B_SZ + mb) = acc[i];
  }
#undef LOAD_A
#undef WRITE_A
#undef COMPUTE
}

// ---------------------------------------------------------------------------
// Kernel C: reduce split-K partials, add b1, relu -> h[m][n]
// ---------------------------------------------------------------------------
__global__ __launch_bounds__(256) void reduce_kernel(const float* __restrict__ h_part,
                                                     const float* __restrict__ b1,
                                                     float* __restrict__ h) {
  const int n = blockIdx.x;
  const int m = threadIdx.x;
  float s = 0.f;
  #pragma unroll 6
  for (int ks = 0; ks < KSPLIT; ++ks)
    s += h_part[((size_t)ks * DHID + n) * B_SZ + m];
  float v = s + b1[n];
  h[(size_t)m * DHID + n] = v > 0.f ? v : 0.f;
}

// ---------------------------------------------------------------------------
// Kernel D: logits = h @ W2^T + b2. One wave per batch row.
// ---------------------------------------------------------------------------
__global__ __launch_bounds__(64) void head_kernel(const float* __restrict__ h,
                                                  const float* __restrict__ W2,
                                                  const float* __restrict__ b2,
                                                  float* __restrict__ logits) {
  const int m = blockIdx.x;
  const int lane = threadIdx.x;
  float hv[12];
  #pragma unroll
  for (int j = 0; j < 12; ++j) hv[j] = h[(size_t)m * DHID + j * 64 + lane];
  #pragma unroll
  for (int c = 0; c < NCLS; ++c) {
    float s = 0.f;
    #pragma unroll
    for (int j = 0; j < 12; ++j) s += hv[j] * W2[c * DHID + j * 64 + lane];
    #pragma unroll
    for (int off = 32; off > 0; off >>= 1) s += __shfl_xor(s, off);
    if (lane == 0) logits[m * NCLS + c] = s + b2[c];
  }
}

// ---------------------------------------------------------------------------
extern "C" void kernel_launch(void* const* d_in, const int* in_sizes, int n_in,
                              void* d_out, int out_size, void* d_ws, size_t ws_size,
                              hipStream_t stream) {
  const float* feat = (const float*)d_in[0];
  const float* W1   = (const float*)d_in[1];
  const float* b1   = (const float*)d_in[2];
  const float* W2   = (const float*)d_in[3];
  const float* b2   = (const float*)d_in[4];

  float* logits   = (float*)d_out;
  float* feat_out = (float*)d_out + (size_t)B_SZ * NCLS;

  char* ws = (char*)d_ws;
  __bf16* pcam   = (__bf16*)ws;                                   // 25.7 MB
  float*  h_part = (float*)(ws + (size_t)B_SZ * KDIM * 2);        // 42*768*256*4 = 33 MB
  float*  h      = (float*)(ws + (size_t)B_SZ * KDIM * 2
                               + (size_t)KSPLIT * DHID * B_SZ * 4); // 786 KB

  pcam_kernel<<<(B_SZ * C_SZ) / 32, 256, 0, stream>>>(feat, feat_out, pcam);
  gemm1_kernel<<<dim3(NT, KSPLIT), 512, 0, stream>>>(pcam, W1, h_part);
  reduce_kernel<<<DHID, 256, 0, stream>>>(h_part, b1, h);
  head_kernel<<<B_SZ, 64, 0, stream>>>(h, W2, b2, logits);
}

// Round 12
// 98.399 us; speedup vs baseline: 1.1737x; 1.0555x over previous
//
#include <hip/hip_runtime.h>
#include <hip/hip_bf16.h>

// Shapes
#define B_SZ   256
#define C_SZ   1024
#define HW     49
#define KDIM   50176        // C*H*W
#define DHID   768
#define NCLS   5

typedef __bf16 bf16x8 __attribute__((ext_vector_type(8)));
typedef float  f32x4  __attribute__((ext_vector_type(4)));

#define GLOAD_LDS16(gsrc, ldst) \
  __builtin_amdgcn_global_load_lds((__attribute__((address_space(1))) void*)(gsrc), \
                                   (__attribute__((address_space(3))) void*)(ldst), 16, 0, 0)

// ---------------------------------------------------------------------------
// Kernel A: per-(b,c) spatial max, pcam = feat*max -> bf16 (ws), copy feat -> out
// ---------------------------------------------------------------------------
__global__ __launch_bounds__(256) void pcam_kernel(const float* __restrict__ feat,
                                                   float* __restrict__ feat_out,
                                                   __bf16* __restrict__ pcam) {
  __shared__ float sv[1568];
  __shared__ float smax[32];
  const int tid = threadIdx.x;
  const size_t base = (size_t)blockIdx.x * 1568;

  const float4* src4 = (const float4*)(feat + base);
  float4* dst4 = (float4*)(feat_out + base);
  #pragma unroll
  for (int i = 0; i < 2; ++i) {
    int idx = tid + i * 256;
    if (idx < 392) {
      float4 v = src4[idx];
      dst4[idx] = v;
      ((float4*)sv)[idx] = v;
    }
  }
  __syncthreads();

  {
    const int r = tid >> 3, p = tid & 7;
    float mx = -INFINITY;
    for (int i = p; i < HW; i += 8) mx = fmaxf(mx, sv[r * HW + i]);
    #pragma unroll
    for (int off = 1; off < 8; off <<= 1) mx = fmaxf(mx, __shfl_xor(mx, off));
    if (p == 0) smax[r] = mx;
  }
  __syncthreads();

  for (int i = tid; i < 1568; i += 256) {
    int r = (i * 1338) >> 16;        // i/49 exact for i<1568
    float v = sv[i] * smax[r];
    pcam[base + i] = (__bf16)v;
  }
}

// ---------------------------------------------------------------------------
// Kernel B (v10 = PER-WAVE PIPELINED STREAMS): across R1-R11, each W1 stream
// advanced one chunk per ~2us block-lockstep period (effective prefetch depth
// <=2, refilled once/period) -> 21 GB/s/CU. This kernel decouples it:
//   - BK=32: per wave per step just 2 B-loads (32B/lane) + 2 A-DMAs.
//   - B: 6-deep STATIC register ring (q0..q5), issued 6 steps ahead.
//   - A: global_load_lds into a 3-buffer LDS ring, issued 2 steps ahead.
//   - ONE s_waitcnt vmcnt(6) + ONE barrier per step. In-order vmem counter:
//     per step issues [A:2, B:2]; 6 newest = {B(t+4),A(t+1),B(t+5)} so
//     vmcnt(6) completes A(t),B(t) while keeping 2-3 steps of B in flight.
//   - 42-step padded loop = outer 7 x inner 6 (all ring indices literal);
//     pad steps issue clamped addresses and skip consume (wave-uniform).
// BM=256 (W1 once), BN=128 (8 waves x 16 cols), KSPLIT=42 -> 252 blocks.
// A source pre-swizzled 16B-unit ^= (m&3), linear LDS dest; af reads use the
// matching XOR (4-way conflict max). Private partials, no atomics.
// ---------------------------------------------------------------------------
#define BM 256
#define BN 128
#define BK 32
#define NT 6
#define KSPLIT 42
#define KSTEPS 1568         // KDIM/BK

__global__ __launch_bounds__(512, 1) void gemm1_kernel(const __bf16* __restrict__ pcam,
                                                       const float* __restrict__ W1,
                                                       float* __restrict__ h_part) {
  __shared__ __bf16 Asm[3][BM * BK];   // 3 x 16 KB ring

  const int tid  = threadIdx.x;
  const int lane = tid & 63;
  const int w    = tid >> 6;        // 0..7 : 16-col n-slab per wave
  const int c_   = lane & 15;
  const int n0   = blockIdx.x * BN;
  const int ks   = blockIdx.y;
  const int s0   = (ks * KSTEPS) / KSPLIT;
  const int s1   = ((ks + 1) * KSTEPS) / KSPLIT;   // 37-38 steps

  // B stream base: lane -> W1 row n0+w*16+c_, k-chunk (lane>>4)*8 floats
  const float* bbase = W1 + (size_t)(n0 + w * 16 + c_) * KDIM + (lane >> 4) * 8;

  // A DMA: 2 instrs/wave; 16B-unit ug=(w*2+i)*64+lane; row m=ug>>2 (4/row);
  // source unit pre-swizzled ^(m&3); LDS dest linear (ug*16B).
  unsigned a_off0, a_off1;
  {
    unsigned ug, m;
    ug = (w * 2 + 0) * 64 + lane; m = ug >> 2;
    a_off0 = m * (unsigned)KDIM + (((ug & 3) ^ (m & 3)) * 8u);
    ug = (w * 2 + 1) * 64 + lane; m = ug >> 2;
    a_off1 = m * (unsigned)KDIM + (((ug & 3) ^ (m & 3)) * 8u);
  }
  const int uoff = (((lane >> 4) ^ (lane & 3)) << 4);  // af byte sub-offset

  f32x4 acc[16];
  #pragma unroll
  for (int i = 0; i < 16; ++i) acc[i] = f32x4{0.f, 0.f, 0.f, 0.f};

  // B register ring, 6 slots, static names only (rule #20)
  f32x4 q0a, q0b, q1a, q1b, q2a, q2b, q3a, q3b, q4a, q4b, q5a, q5b;

  // ---- prologue: A(s0)->buf0, A(s0+1)->buf1; B(s0..s0+5)->slots 0..5
  GLOAD_LDS16(pcam + a_off0 + (unsigned)s0 * BK, (char*)Asm[0] + (w * 2 + 0) * 1024);
  GLOAD_LDS16(pcam + a_off1 + (unsigned)s0 * BK, (char*)Asm[0] + (w * 2 + 1) * 1024);
  GLOAD_LDS16(pcam + a_off0 + (unsigned)(s0 + 1) * BK, (char*)Asm[1] + (w * 2 + 0) * 1024);
  GLOAD_LDS16(pcam + a_off1 + (unsigned)(s0 + 1) * BK, (char*)Asm[1] + (w * 2 + 1) * 1024);
  q0a = *(const f32x4*)(bbase + (size_t)(s0 + 0) * BK); q0b = *(const f32x4*)(bbase + (size_t)(s0 + 0) * BK + 4);
  q1a = *(const f32x4*)(bbase + (size_t)(s0 + 1) * BK); q1b = *(const f32x4*)(bbase + (size_t)(s0 + 1) * BK + 4);
  q2a = *(const f32x4*)(bbase + (size_t)(s0 + 2) * BK); q2b = *(const f32x4*)(bbase + (size_t)(s0 + 2) * BK + 4);
  q3a = *(const f32x4*)(bbase + (size_t)(s0 + 3) * BK); q3b = *(const f32x4*)(bbase + (size_t)(s0 + 3) * BK + 4);
  q4a = *(const f32x4*)(bbase + (size_t)(s0 + 4) * BK); q4b = *(const f32x4*)(bbase + (size_t)(s0 + 4) * BK + 4);
  q5a = *(const f32x4*)(bbase + (size_t)(s0 + 5) * BK); q5b = *(const f32x4*)(bbase + (size_t)(s0 + 5) * BK + 4);

#define STEPQ(JI, QA, QB) do { \
    const int t = s0 + jo * 6 + (JI); \
    asm volatile("s_waitcnt vmcnt(6)" ::: "memory"); \
    __builtin_amdgcn_s_barrier(); \
    const bool act = (t < s1); \
    bf16x8 bfr; \
    if (act) { \
      bfr[0] = (__bf16)QA[0]; bfr[1] = (__bf16)QA[1]; bfr[2] = (__bf16)QA[2]; bfr[3] = (__bf16)QA[3]; \
      bfr[4] = (__bf16)QB[0]; bfr[5] = (__bf16)QB[1]; bfr[6] = (__bf16)QB[2]; bfr[7] = (__bf16)QB[3]; \
    } \
    { const int ta = (t + 2 < s1) ? (t + 2) : (s1 - 1); \
      GLOAD_LDS16(pcam + a_off0 + (unsigned)ta * BK, (char*)Asm[((JI) + 2) % 3] + (w * 2 + 0) * 1024); \
      GLOAD_LDS16(pcam + a_off1 + (unsigned)ta * BK, (char*)Asm[((JI) + 2) % 3] + (w * 2 + 1) * 1024); \
      const int tb = (t + 6 < s1) ? (t + 6) : (s1 - 1); \
      QA = *(const f32x4*)(bbase + (size_t)tb * BK); \
      QB = *(const f32x4*)(bbase + (size_t)tb * BK + 4); } \
    if (act) { \
      _Pragma("unroll") \
      for (int i = 0; i < 16; ++i) { \
        const int m = i * 16 + c_; \
        const bf16x8 af = *(const bf16x8*)((const char*)Asm[(JI) % 3] + m * 64 + uoff); \
        acc[i] = __builtin_amdgcn_mfma_f32_16x16x32_bf16(af, bfr, acc[i], 0, 0, 0); \
      } \
    } \
  } while (0)

  for (int jo = 0; jo < 7; ++jo) {     // 7 x 6 = 42 padded steps >= 38
    STEPQ(0, q0a, q0b);
    STEPQ(1, q1a, q1b);
    STEPQ(2, q2a, q2b);
    STEPQ(3, q3a, q3b);
    STEPQ(4, q4a, q4b);
    STEPQ(5, q5a, q5b);
  }
#undef STEPQ

  // ---- epilogue: private partial slice [ks][n][m], coalesced float4 stores
  float* out = h_part + (size_t)ks * DHID * B_SZ;
  const int n = n0 + w * 16 + c_;
  #pragma unroll
  for (int i = 0; i < 16; ++i) {
    const int mb = i * 16 + (lane >> 4) * 4;
    *(f32x4*)(out + (size_t)n * B_SZ + mb) = acc[i];
  }
}

// ---------------------------------------------------------------------------
// Kernel C: reduce split-K partials, add b1, relu -> h[m][n]
// ---------------------------------------------------------------------------
__global__ __launch_bounds__(256) void reduce_kernel(const float* __restrict__ h_part,
                                                     const float* __restrict__ b1,
                                                     float* __restrict__ h) {
  const int n = blockIdx.x;
  const int m = threadIdx.x;
  float s = 0.f;
  #pragma unroll 6
  for (int ks = 0; ks < KSPLIT; ++ks)
    s += h_part[((size_t)ks * DHID + n) * B_SZ + m];
  float v = s + b1[n];
  h[(size_t)m * DHID + n] = v > 0.f ? v : 0.f;
}

// ---------------------------------------------------------------------------
// Kernel D: logits = h @ W2^T + b2. One wave per batch row.
// ---------------------------------------------------------------------------
__global__ __launch_bounds__(64) void head_kernel(const float* __restrict__ h,
                                                  const float* __restrict__ W2,
                                                  const float* __restrict__ b2,
                                                  float* __restrict__ logits) {
  const int m = blockIdx.x;
  const int lane = threadIdx.x;
  float hv[12];
  #pragma unroll
  for (int j = 0; j < 12; ++j) hv[j] = h[(size_t)m * DHID + j * 64 + lane];
  #pragma unroll
  for (int c = 0; c < NCLS; ++c) {
    float s = 0.f;
    #pragma unroll
    for (int j = 0; j < 12; ++j) s += hv[j] * W2[c * DHID + j * 64 + lane];
    #pragma unroll
    for (int off = 32; off > 0; off >>= 1) s += __shfl_xor(s, off);
    if (lane == 0) logits[m * NCLS + c] = s + b2[c];
  }
}

// ---------------------------------------------------------------------------
extern "C" void kernel_launch(void* const* d_in, const int* in_sizes, int n_in,
                              void* d_out, int out_size, void* d_ws, size_t ws_size,
                              hipStream_t stream) {
  const float* feat = (const float*)d_in[0];
  const float* W1   = (const float*)d_in[1];
  const float* b1   = (const float*)d_in[2];
  const float* W2   = (const float*)d_in[3];
  const float* b2   = (const float*)d_in[4];

  float* logits   = (float*)d_out;
  float* feat_out = (float*)d_out + (size_t)B_SZ * NCLS;

  char* ws = (char*)d_ws;
  __bf16* pcam   = (__bf16*)ws;                                   // 25.7 MB
  float*  h_part = (float*)(ws + (size_t)B_SZ * KDIM * 2);        // 42*768*256*4 = 33 MB
  float*  h      = (float*)(ws + (size_t)B_SZ * KDIM * 2
                               + (size_t)KSPLIT * DHID * B_SZ * 4); // 786 KB

  pcam_kernel<<<(B_SZ * C_SZ) / 32, 256, 0, stream>>>(feat, feat_out, pcam);
  gemm1_kernel<<<dim3(NT, KSPLIT), 512, 0, stream>>>(pcam, W1, h_part);
  reduce_kernel<<<DHID, 256, 0, stream>>>(h_part, b1, h);
  head_kernel<<<B_SZ, 64, 0, stream>>>(h, W2, b2, logits);
}

// Round 13
// 93.926 us; speedup vs baseline: 1.2296x; 1.0476x over previous
//
#include <hip/hip_runtime.h>
#include <hip/hip_bf16.h>

// Shapes
#define B_SZ   256
#define C_SZ   1024
#define HW     49
#define KDIM   50176        // C*H*W
#define DHID   768
#define NCLS   5

typedef __bf16 bf16x8 __attribute__((ext_vector_type(8)));
typedef __bf16 bf16x4 __attribute__((ext_vector_type(4)));
typedef float  f32x4  __attribute__((ext_vector_type(4)));

#define GLOAD_LDS16(gsrc, ldst) \
  __builtin_amdgcn_global_load_lds((__attribute__((address_space(1))) void*)(gsrc), \
                                   (__attribute__((address_space(3))) void*)(ldst), 16, 0, 0)

#define BARRIER() do { \
    asm volatile("s_waitcnt lgkmcnt(0)" ::: "memory"); \
    __builtin_amdgcn_s_barrier(); \
    asm volatile("" ::: "memory"); \
  } while (0)

// ---------------------------------------------------------------------------
// Kernel A: per-(b,c) spatial max, pcam = feat*max -> bf16 (ws), copy feat -> out
// ---------------------------------------------------------------------------
__global__ __launch_bounds__(256) void pcam_kernel(const float* __restrict__ feat,
                                                   float* __restrict__ feat_out,
                                                   __bf16* __restrict__ pcam) {
  __shared__ float sv[1568];
  __shared__ float smax[32];
  const int tid = threadIdx.x;
  const size_t base = (size_t)blockIdx.x * 1568;

  const float4* src4 = (const float4*)(feat + base);
  float4* dst4 = (float4*)(feat_out + base);
  #pragma unroll
  for (int i = 0; i < 2; ++i) {
    int idx = tid + i * 256;
    if (idx < 392) {
      float4 v = src4[idx];
      dst4[idx] = v;
      ((float4*)sv)[idx] = v;
    }
  }
  __syncthreads();

  {
    const int r = tid >> 3, p = tid & 7;
    float mx = -INFINITY;
    for (int i = p; i < HW; i += 8) mx = fmaxf(mx, sv[r * HW + i]);
    #pragma unroll
    for (int off = 1; off < 8; off <<= 1) mx = fmaxf(mx, __shfl_xor(mx, off));
    if (p == 0) smax[r] = mx;
  }
  __syncthreads();

  for (int i = tid; i < 1568; i += 256) {
    int r = (i * 1338) >> 16;        // i/49 exact for i<1568
    float v = sv[i] * smax[r];
    pcam[base + i] = (__bf16)v;
  }
}

// ---------------------------------------------------------------------------
// Kernel B (v11 = COALESCED W1): R1-R12 all read W1 in 32-64B granules
// scattered across 200KB-strided rows (the LDS-linear-dest constraint of
// global_load_lds pushes the row-scatter onto the GLOBAL side). Kernels with
// >=512B/instr contiguous hit 7 TB/s on this chip; mine got 2-4. Fix:
// B is REG-STAGED with coalesced reads -- one instr = 4 rows x 256B
// CONTIGUOUS (lane&15 indexes k WITHIN a row) -- then fp32->bf16 cvt in
// regs and XOR-swizzled ds_write_b64 (the transpose/scatter lives in LDS
// addressing, which costs nothing on the fabric). Fragments via swizzled
// ds_read_b128. A (pcam, L2/L3-served) stays DMA-staged as before.
// Double-buffered A+B (96KB, 1 blk/CU), one vmcnt(0)+barrier per K-step
// (R4/R5 proved drain vs no-drain is a non-factor). bf16 partials.
// BM=256 (W1 once), BN=128, BK=64, NT=6, KSPLIT=42 -> 252 blocks.
// ---------------------------------------------------------------------------
#define BM 256
#define BN 128
#define BK 64
#define NT 6
#define KSPLIT 42
#define KSTEPS 784          // KDIM/BK

__global__ __launch_bounds__(512, 1) void gemm1_kernel(const __bf16* __restrict__ pcam,
                                                       const float* __restrict__ W1,
                                                       __bf16* __restrict__ h_part) {
  __shared__ __bf16 Asm[2][BM * BK];   // 2 x 32 KB
  __shared__ __bf16 Bsm[2][BN * BK];   // 2 x 16 KB

  const int tid  = threadIdx.x;
  const int lane = tid & 63;
  const int w    = tid >> 6;        // 0..7 : wave owns n-slab w*16..w*16+15
  const int c_   = lane & 15;
  const int q_   = lane >> 4;       // 0..3
  const int n0   = blockIdx.x * BN;
  const int ks   = blockIdx.y;
  const int s0   = (ks * KSTEPS) / KSPLIT;
  const int s1   = ((ks + 1) * KSTEPS) / KSPLIT;

  // ---- A staging (pcam bf16, global_load_lds): 2048 16B-units, 4/thread.
  // unit ug = it*512+tid; row m=ug>>3; source unit (ug&7)^(m&7); dest linear.
  unsigned a_off[4];
  #pragma unroll
  for (int it = 0; it < 4; ++it) {
    const unsigned ug = it * 512 + tid;
    const unsigned m  = ug >> 3;
    a_off[it] = m * (unsigned)KDIM + (((ug & 7) ^ (m & 7)) * 8u);
  }

  // ---- B staging (COALESCED): instr i reads rows w*16+i*4+q_, bytes
  // (lane&15)*16 within the row's 256B k-chunk -> 4 x 256B contiguous.
  const float* bsrc[4];
  #pragma unroll
  for (int i = 0; i < 4; ++i)
    bsrc[i] = W1 + (size_t)(n0 + w * 16 + i * 4 + q_) * KDIM + c_ * 4;

  // B ds_write addressing: row r = w*16+i*4+q_, 8B-unit u8 = c_ (k' = u8*4..+3)
  // phys 16B-unit = (u8>>1)^(r&7), half = u8&1.
  int bwr[4];
  #pragma unroll
  for (int i = 0; i < 4; ++i) {
    const int r = w * 16 + i * 4 + q_;
    bwr[i] = r * 128 + (((c_ >> 1) ^ (r & 7)) << 4) + ((c_ & 1) << 3);
  }
  const int rn = w * 16 + c_;       // fragment row (local n)

  f32x4 acc[16];
  #pragma unroll
  for (int i = 0; i < 16; ++i) acc[i] = f32x4{0.f, 0.f, 0.f, 0.f};

  f32x4 bq0, bq1, bq2, bq3;          // B stage regs (one K-step)

#define ISSUE_A(bi, s) do { \
    const unsigned ka = (unsigned)(s) * BK; \
    _Pragma("unroll") \
    for (int it = 0; it < 4; ++it) \
      GLOAD_LDS16(pcam + a_off[it] + ka, (char*)Asm[bi] + it * 8192 + w * 1024); \
  } while (0)

#define ISSUE_B(s) do { \
    const size_t kb = (size_t)(s) * BK; \
    bq0 = *(const f32x4*)(bsrc[0] + kb); \
    bq1 = *(const f32x4*)(bsrc[1] + kb); \
    bq2 = *(const f32x4*)(bsrc[2] + kb); \
    bq3 = *(const f32x4*)(bsrc[3] + kb); \
  } while (0)

#define WRITE_B(bi) do { \
    _Pragma("unroll") \
    for (int i = 0; i < 4; ++i) { \
      const f32x4 v = (i == 0) ? bq0 : (i == 1) ? bq1 : (i == 2) ? bq2 : bq3; \
      bf16x4 bv; \
      bv[0] = (__bf16)v[0]; bv[1] = (__bf16)v[1]; \
      bv[2] = (__bf16)v[2]; bv[3] = (__bf16)v[3]; \
      *(bf16x4*)((char*)Bsm[bi] + bwr[i]) = bv; \
    } \
  } while (0)

#define COMPUTE(bi) do { \
    _Pragma("unroll") \
    for (int ksub = 0; ksub < 2; ++ksub) { \
      const int u = ksub * 4 + q_; \
      const bf16x8 bfr = *(const bf16x8*)((const char*)Bsm[bi] + rn * 128 + ((u ^ (rn & 7)) << 4)); \
      _Pragma("unroll") \
      for (int i = 0; i < 16; ++i) { \
        const int m = i * 16 + c_; \
        const bf16x8 af = *(const bf16x8*)((const char*)Asm[bi] + m * 128 + ((u ^ (m & 7)) << 4)); \
        acc[i] = __builtin_amdgcn_mfma_f32_16x16x32_bf16(af, bfr, acc[i], 0, 0, 0); \
      } \
    } \
  } while (0)

  // ---- prologue
  ISSUE_A(0, s0);
  ISSUE_B(s0);
  asm volatile("s_waitcnt vmcnt(0)" ::: "memory");
  WRITE_B(0);
  BARRIER();
  if (s0 + 1 < s1) { ISSUE_A(1, s0 + 1); ISSUE_B(s0 + 1); }

  for (int s = s0; s < s1; ++s) {
    const int cur = (s - s0) & 1;
    COMPUTE(cur);
    if (s + 1 < s1) {
      asm volatile("s_waitcnt vmcnt(0)" ::: "memory");  // A(s+1) DMA + B(s+1) regs
      WRITE_B(cur ^ 1);
    }
    BARRIER();
    if (s + 2 < s1) { ISSUE_A(cur, s + 2); ISSUE_B(s + 2); }
  }

  // ---- epilogue: bf16 partial slice [ks][n][m] (m fastest, 4 per lane)
  __bf16* out = h_part + (size_t)ks * DHID * B_SZ;
  const int n = n0 + w * 16 + c_;
  #pragma unroll
  for (int i = 0; i < 16; ++i) {
    const int mb = i * 16 + q_ * 4;
    bf16x4 pv;
    pv[0] = (__bf16)acc[i][0]; pv[1] = (__bf16)acc[i][1];
    pv[2] = (__bf16)acc[i][2]; pv[3] = (__bf16)acc[i][3];
    *(bf16x4*)(out + (size_t)n * B_SZ + mb) = pv;
  }
#undef ISSUE_A
#undef ISSUE_B
#undef WRITE_B
#undef COMPUTE
}

// ---------------------------------------------------------------------------
// Kernel C: reduce bf16 split-K partials, add b1, relu -> h[m][n] (fp32)
// ---------------------------------------------------------------------------
__global__ __launch_bounds__(256) void reduce_kernel(const __bf16* __restrict__ h_part,
                                                     const float* __restrict__ b1,
                                                     float* __restrict__ h) {
  const int n = blockIdx.x;
  const int m = threadIdx.x;
  float s = 0.f;
  #pragma unroll 6
  for (int ks = 0; ks < KSPLIT; ++ks)
    s += (float)h_part[((size_t)ks * DHID + n) * B_SZ + m];
  float v = s + b1[n];
  h[(size_t)m * DHID + n] = v > 0.f ? v : 0.f;
}

// ---------------------------------------------------------------------------
// Kernel D: logits = h @ W2^T + b2. One wave per batch row.
// ---------------------------------------------------------------------------
__global__ __launch_bounds__(64) void head_kernel(const float* __restrict__ h,
                                                  const float* __restrict__ W2,
                                                  const float* __restrict__ b2,
                                                  float* __restrict__ logits) {
  const int m = blockIdx.x;
  const int lane = threadIdx.x;
  float hv[12];
  #pragma unroll
  for (int j = 0; j < 12; ++j) hv[j] = h[(size_t)m * DHID + j * 64 + lane];
  #pragma unroll
  for (int c = 0; c < NCLS; ++c) {
    float s = 0.f;
    #pragma unroll
    for (int j = 0; j < 12; ++j) s += hv[j] * W2[c * DHID + j * 64 + lane];
    #pragma unroll
    for (int off = 32; off > 0; off >>= 1) s += __shfl_xor(s, off);
    if (lane == 0) logits[m * NCLS + c] = s + b2[c];
  }
}

// ---------------------------------------------------------------------------
extern "C" void kernel_launch(void* const* d_in, const int* in_sizes, int n_in,
                              void* d_out, int out_size, void* d_ws, size_t ws_size,
                              hipStream_t stream) {
  const float* feat = (const float*)d_in[0];
  const float* W1   = (const float*)d_in[1];
  const float* b1   = (const float*)d_in[2];
  const float* W2   = (const float*)d_in[3];
  const float* b2   = (const float*)d_in[4];

  float* logits   = (float*)d_out;
  float* feat_out = (float*)d_out + (size_t)B_SZ * NCLS;

  char* ws = (char*)d_ws;
  __bf16* pcam   = (__bf16*)ws;                                   // 25.7 MB
  __bf16* h_part = (__bf16*)(ws + (size_t)B_SZ * KDIM * 2);       // 42*768*256*2 = 16.5 MB
  float*  h      = (float*)(ws + (size_t)B_SZ * KDIM * 2
                               + (size_t)KSPLIT * DHID * B_SZ * 2); // 786 KB

  pcam_kernel<<<(B_SZ * C_SZ) / 32, 256, 0, stream>>>(feat, feat_out, pcam);
  gemm1_kernel<<<dim3(NT, KSPLIT), 512, 0, stream>>>(pcam, W1, h_part);
  reduce_kernel<<<DHID, 256, 0, stream>>>(h_part, b1, h);
  head_kernel<<<B_SZ, 64, 0, stream>>>(h, W2, b2, logits);
}